// Round 2
// 336.553 us; speedup vs baseline: 1.0296x; 1.0296x over previous
//
#include <hip/hip_runtime.h>

// Transformer-XL attention, MI355X gfx950.
// All tensors fp32 in global (per reference); internal path bf16 MFMA + fp32 acc.
// B=4 TQ=1024 TK=1536 D=1024 H=16 DV=64, mem=512 causal: j <= i+512.
//
// Round-9: compile fix only (unbalanced paren in EPI==2 epilogue).
// Round-8 structure unchanged: fused_proj as 256x256 8-wave 4-phase schedule
// (T2+T3+T4+T5): 4-slot K-half LDS rings, counted vmcnt(4) across barriers,
// XOR bank swizzle on stage-source + ds_read, setprio around MFMA clusters.
// Round-7 postmortem: m97-style 128-tile body sat at 543 TF / MfmaUtil 22% --
// structure-bound (drain-per-K-step), not memory-bound (HBM 15%).

typedef unsigned short u16;
typedef __attribute__((ext_vector_type(8))) short short8;   // 8 bf16 (MFMA A/B frag)
typedef __attribute__((ext_vector_type(4))) float floatx4;  // MFMA C/D frag

__device__ __forceinline__ float bf2f(u16 u) {
    union { unsigned int i; float f; } w; w.i = ((unsigned int)u) << 16; return w.f;
}
__device__ __forceinline__ u16 f2bf(float f) {
    union { unsigned int i; float f; } w; w.f = f;
    unsigned int u = w.i;
    return (u16)((u + 0x7FFFu + ((u >> 16) & 1u)) >> 16);
}

// async global->LDS, 16B per lane; LDS dest = wave-uniform base + lane*16
__device__ __forceinline__ void gl_lds16(const u16* g, u16* lds) {
    __builtin_amdgcn_global_load_lds(
        (const __attribute__((address_space(1))) void*)g,
        (__attribute__((address_space(3))) void*)lds, 16, 0, 0);
}

// ---------------------------------------------------------------------------
// Fused fp32 -> bf16 conversion for query/key_value/relative (grid.y selects)
// ---------------------------------------------------------------------------
__global__ __launch_bounds__(256) void cvt3_kernel(
    const float* __restrict__ x0, u16* __restrict__ y0, int n0,
    const float* __restrict__ x1, u16* __restrict__ y1, int n1,
    const float* __restrict__ x2, u16* __restrict__ y2, int n2)
{
    const int which = blockIdx.y;
    const float* x = (which == 0) ? x0 : (which == 1) ? x1 : x2;
    u16* y         = (which == 0) ? y0 : (which == 1) ? y1 : y2;
    const int n    = (which == 0) ? n0 : (which == 1) ? n1 : n2;
    const int i = (blockIdx.x * 256 + threadIdx.x) * 8;
    if (i >= n) return;
    float4 a = *(const float4*)&x[i];
    float4 b = *(const float4*)&x[i + 4];
    short8 o;
    o[0] = (short)f2bf(a.x); o[1] = (short)f2bf(a.y);
    o[2] = (short)f2bf(a.z); o[3] = (short)f2bf(a.w);
    o[4] = (short)f2bf(b.x); o[5] = (short)f2bf(b.y);
    o[6] = (short)f2bf(b.z); o[7] = (short)f2bf(b.w);
    *(short8*)&y[i] = o;
}

// ---------------------------------------------------------------------------
// Fused weight transpose + cvt: 5 weights in one dispatch (grid.z selects).
// WT[n][k] = bf16(W[k][n]); W is 1024x1024 fp32.
// ---------------------------------------------------------------------------
__global__ __launch_bounds__(256) void transpose5_kernel(
    const float* __restrict__ Wq, const float* __restrict__ Wk,
    const float* __restrict__ Wr, const float* __restrict__ Wv,
    const float* __restrict__ Wo,
    u16* __restrict__ WqT, u16* __restrict__ WkrT,
    u16* __restrict__ WvT, u16* __restrict__ WoT)
{
    const int z = blockIdx.z;
    const float* W; u16* WT; int dst_ld, dst_koff;
    switch (z) {
        case 0: W = Wq; WT = WqT;  dst_ld = 1024; dst_koff = 0;    break;
        case 1: W = Wk; WT = WkrT; dst_ld = 2048; dst_koff = 0;    break;
        case 2: W = Wr; WT = WkrT; dst_ld = 2048; dst_koff = 1024; break;
        case 3: W = Wv; WT = WvT;  dst_ld = 1024; dst_koff = 0;    break;
        default:W = Wo; WT = WoT;  dst_ld = 1024; dst_koff = 0;    break;
    }
    __shared__ u16 ts[64][72];
    const int k0 = blockIdx.x * 64, n0 = blockIdx.y * 64;
    const int r  = threadIdx.x >> 2;
    const int c4 = (threadIdx.x & 3) << 4;
    const float* src = &W[(size_t)(k0 + r) * 1024 + n0 + c4];
    for (int j = 0; j < 16; j += 4) {
        float4 a = *(const float4*)(src + j);
        ts[r][c4 + j + 0] = f2bf(a.x);
        ts[r][c4 + j + 1] = f2bf(a.y);
        ts[r][c4 + j + 2] = f2bf(a.z);
        ts[r][c4 + j + 3] = f2bf(a.w);
    }
    __syncthreads();
    short8 t0, t1;
    for (int j = 0; j < 8; j++) t0[j] = (short)ts[c4 + j][r];
    for (int j = 0; j < 8; j++) t1[j] = (short)ts[c4 + 8 + j][r];
    u16* dst = &WT[(size_t)(n0 + r) * dst_ld + dst_koff + k0 + c4];
    *(short8*)dst       = t0;
    *(short8*)(dst + 8) = t1;
}

// ---------------------------------------------------------------------------
// wuvb[h][k] (bf16, [16][2048]): k<1024 -> Wk[k][h*64+:]·u ; else Wr·v
// ---------------------------------------------------------------------------
__global__ __launch_bounds__(256) void wuv_kernel(
    const float* __restrict__ Wk, const float* __restrict__ Wr,
    const float* __restrict__ u, const float* __restrict__ v,
    u16* __restrict__ wuvb)
{
    int idx = blockIdx.x * 256 + threadIdx.x;
    int c = idx >> 4, h = idx & 15;
    float au = 0.f, av = 0.f;
    for (int d = 0; d < 64; d++) {
        au += Wk[(size_t)c * 1024 + h * 64 + d] * u[d];
        av += Wr[(size_t)c * 1024 + h * 64 + d] * v[d];
    }
    wuvb[h * 2048 + c]        = f2bf(au);
    wuvb[h * 2048 + 1024 + c] = f2bf(av);
}

// ---------------------------------------------------------------------------
// Old 128x128 GEMM tile body (m97-style), kept for out_gemm (EPI 3 only):
// raw fp32 out[m*1024 + col] (split-K partial)
// ---------------------------------------------------------------------------
template <int EPI>
__device__ __forceinline__ void gemm_body(
    const u16* __restrict__ A0, const u16* __restrict__ A1,
    const u16* __restrict__ WT, void* __restrict__ out,
    int Kld, int kbeg, int kend, int Ksplit, int T,
    int bm, int bn, u16* As, u16* Ws)
{
    const int tid = threadIdx.x;
    const int wave = tid >> 6, lane = tid & 63;
    const int wm = wave >> 1, wn = wave & 1;
    const int l16 = lane & 15, quad = lane >> 4;

    floatx4 acc[4][4];
    const floatx4 zf = {0.f, 0.f, 0.f, 0.f};
    for (int i = 0; i < 4; i++) for (int j = 0; j < 4; j++) acc[i][j] = zf;

    const int m_base = bm * 128, n_base = bn * 128;
    const int rl = lane >> 2;          // 0..15 row within 16-row DMA group
    const int cl = (lane & 3) * 8;     // 0,8,16,24 col elems (16B)

    for (int k0 = kbeg; k0 < kend; k0 += 32) {
        const u16* Aptr; int kk;
        if (k0 < Ksplit) { Aptr = A0; kk = k0; } else { Aptr = A1; kk = k0 - Ksplit; }
        __syncthreads();
        for (int half = 0; half < 2; half++) {
            const int r = wave * 32 + half * 16;  // wave-uniform LDS base row
            gl_lds16(Aptr + (size_t)(m_base + r + rl) * 1024 + kk + cl, &As[r * 32]);
            gl_lds16(WT   + (size_t)(n_base + r + rl) * Kld  + k0 + cl, &Ws[r * 32]);
        }
        __syncthreads();

        short8 af[4], bf[4];
        for (int i = 0; i < 4; i++) {
            af[i] = *(const short8*)&As[(wm * 64 + i * 16 + l16) * 32 + quad * 8];
            bf[i] = *(const short8*)&Ws[(wn * 64 + i * 16 + l16) * 32 + quad * 8];
        }
        for (int i = 0; i < 4; i++)
            for (int j = 0; j < 4; j++)
                acc[i][j] = __builtin_amdgcn_mfma_f32_16x16x32_bf16(af[i], bf[j], acc[i][j], 0, 0, 0);
    }

    for (int i = 0; i < 4; i++) {
        for (int rg = 0; rg < 4; rg++) {
            const int m = m_base + wm * 64 + i * 16 + quad * 4 + rg;
            float* op = (float*)out;
            for (int j = 0; j < 4; j++) {
                const int col = n_base + wn * 64 + j * 16 + l16;
                op[(size_t)m * 1024 + col] = acc[i][j][rg];
            }
        }
    }
}

// ---------------------------------------------------------------------------
// 256x256 8-wave deep-pipelined GEMM body (reconstructed HK schedule).
//   BK=64 = 2 K-halves (ks) of 32 elems. LDS: per matrix a 4-slot ring of
//   [256 rows][32 elems] bf16 (16KB/slot) -> 128KB total.
//   phase(ph): ks=ph>>1, mh=ph&1. ph0=(ks0,mh0) ph1=(ks0,mh1) ph2=(ks1,mh0)
//   ph3=(ks1,mh1). B frags read at mh0, held in regs for mh1.
//   Stage stream (1 half / phase): ph0: A-ks1(t+1)  ph1: B-ks1(t+1)
//                                  ph2: A-ks0(t+2)  ph3: B-ks0(t+2)
//   Slot of (tile,ks) = (2*tile+ks)&3 -> every stage target was last read
//   at least one barrier before the stage issues (checked for all phases).
//   Sync: one s_barrier per phase; counted s_waitcnt vmcnt(4) at tile entry
//   (2 halves = 4 loads stay in flight across barriers); vmcnt(0) only at
//   the last tile. setprio(1) around each 16-MFMA cluster.
//   T2 swizzle: 16B chunk index ^= (row&3), applied on the *global source*
//   column during stage (global_load_lds writes LDS linearly) and on the
//   ds_read address.
// ---------------------------------------------------------------------------
__device__ __forceinline__ void stage_half(
    const u16* __restrict__ src, int src_ld, int row_base, int col_base,
    u16* lds_slot, int wave, int lane)
{
    const int r = wave * 16 + (lane >> 2);                        // row in half
    const int c = (((lane & 3) ^ ((lane >> 2) & 3)) << 3);        // pre-swizzled col
    gl_lds16(src + (size_t)(row_base + r) * src_ld + col_base + c,
             lds_slot + wave * 512);
    gl_lds16(src + (size_t)(row_base + 128 + r) * src_ld + col_base + c,
             lds_slot + 4096 + wave * 512);
}

template <int EPI, int T>
__device__ __forceinline__ void gemm256_body(
    const u16* __restrict__ A0, const u16* __restrict__ A1,
    const u16* __restrict__ WT, void* __restrict__ out,
    int Kld, int NT, int KsplitTile, int bm, int bn,
    u16* As, u16* Bs)
{
    const int tid  = threadIdx.x;
    const int wave = tid >> 6, lane = tid & 63;
    const int wm = wave >> 2, wn = wave & 3;       // 2M x 4N wave grid
    const int l16 = lane & 15, quad = lane >> 4;
    const int m_base = bm * 256, n_base = bn * 256;

    floatx4 acc[8][4];
    const floatx4 zf = {0.f, 0.f, 0.f, 0.f};
    #pragma unroll
    for (int i = 0; i < 8; i++)
        #pragma unroll
        for (int j = 0; j < 4; j++) acc[i][j] = zf;

    // --- prologue: 6 halves = tile0 (4) + tile1 ks0 (2) ---
    {
        const u16* sa0 = (0 < KsplitTile) ? A0 : A1;
        stage_half(sa0, 1024, m_base, 0,  As + 0 * 8192, wave, lane); // A t0 ks0
        stage_half(WT,  Kld,  n_base, 0,  Bs + 0 * 8192, wave, lane); // B t0 ks0
        stage_half(sa0, 1024, m_base, 32, As + 1 * 8192, wave, lane); // A t0 ks1
        stage_half(WT,  Kld,  n_base, 32, Bs + 1 * 8192, wave, lane); // B t0 ks1
        const u16* sa1 = (1 < KsplitTile) ? A0 : A1;
        const int  c1  = (1 < KsplitTile) ? 64 : (1 - KsplitTile) * 64;
        stage_half(sa1, 1024, m_base, c1, As + 2 * 8192, wave, lane); // A t1 ks0
        stage_half(WT,  Kld,  n_base, 64, Bs + 2 * 8192, wave, lane); // B t1 ks0
    }

    for (int t = 0; t < NT; ++t) {
        // counted vmcnt: keep the 2 newest halves (tile t+1 ks0) in flight.
        if (t + 1 < NT) asm volatile("s_waitcnt vmcnt(4)" ::: "memory");
        else            asm volatile("s_waitcnt vmcnt(0)" ::: "memory");
        __builtin_amdgcn_s_barrier();

        short8 bfr[4];
        #pragma unroll
        for (int ph = 0; ph < 4; ++ph) {
            if (ph) __builtin_amdgcn_s_barrier();
            const int ks = ph >> 1, mh = ph & 1;

            // ---- stage one half (into a slot freed >=1 barrier ago) ----
            if (ph == 0) {
                if (t + 1 < NT) {
                    const int tt = t + 1;
                    const u16* sa = (tt < KsplitTile) ? A0 : A1;
                    const int cb = (tt < KsplitTile ? tt : tt - KsplitTile) * 64 + 32;
                    stage_half(sa, 1024, m_base, cb, As + ((2 * tt + 1) & 3) * 8192, wave, lane);
                }
            } else if (ph == 1) {
                if (t + 1 < NT)
                    stage_half(WT, Kld, n_base, (t + 1) * 64 + 32,
                               Bs + ((2 * (t + 1) + 1) & 3) * 8192, wave, lane);
            } else if (ph == 2) {
                if (t + 2 < NT) {
                    const int tt = t + 2;
                    const u16* sa = (tt < KsplitTile) ? A0 : A1;
                    const int cb = (tt < KsplitTile ? tt : tt - KsplitTile) * 64;
                    stage_half(sa, 1024, m_base, cb, As + ((2 * tt) & 3) * 8192, wave, lane);
                }
            } else {
                if (t + 2 < NT)
                    stage_half(WT, Kld, n_base, (t + 2) * 64,
                               Bs + ((2 * (t + 2)) & 3) * 8192, wave, lane);
            }

            // ---- ds_read fragments (swizzled) ----
            const u16* Aslot = As + ((2 * t + ks) & 3) * 8192;
            const u16* Bslot = Bs + ((2 * t + ks) & 3) * 8192;
            if (mh == 0) {
                #pragma unroll
                for (int nj = 0; nj < 4; ++nj) {
                    const int row = wn * 64 + nj * 16 + l16;
                    bfr[nj] = *(const short8*)&Bslot[row * 32 + (((quad ^ row) & 3) << 3)];
                }
            }
            short8 af[4];
            #pragma unroll
            for (int mi = 0; mi < 4; ++mi) {
                const int row = wm * 128 + mh * 64 + mi * 16 + l16;
                af[mi] = *(const short8*)&Aslot[row * 32 + (((quad ^ row) & 3) << 3)];
            }

            __builtin_amdgcn_s_setprio(1);
            #pragma unroll
            for (int mi = 0; mi < 4; ++mi)
                #pragma unroll
                for (int nj = 0; nj < 4; ++nj)
                    acc[mh * 4 + mi][nj] = __builtin_amdgcn_mfma_f32_16x16x32_bf16(
                        af[mi], bfr[nj], acc[mh * 4 + mi][nj], 0, 0, 0);
            __builtin_amdgcn_s_setprio(0);
        }
    }

    // ---- epilogue ----
    u16* op = (u16*)out;
    #pragma unroll
    for (int mi = 0; mi < 8; ++mi) {
        #pragma unroll
        for (int rg = 0; rg < 4; ++rg) {
            const int m = m_base + wm * 128 + mi * 16 + quad * 4 + rg;
            const int b = m / T, tk = m % T;   // T is compile-time -> magic mul
            #pragma unroll
            for (int nj = 0; nj < 4; ++nj) {
                const int col = n_base + wn * 64 + nj * 16 + l16;
                const int h = col >> 6, d = col & 63;
                if (EPI == 0) {
                    op[(((size_t)(b * 16 + h) * T + tk) << 6) + d] = f2bf(acc[mi][nj][rg]);
                } else {  // EPI == 2: head-transposed V^T
                    op[((size_t)(b * 16 + h) * 64 + d) * 1536 + tk] = f2bf(acc[mi][nj][rg]);
                }
            }
        }
    }
}

// ---------------------------------------------------------------------------
// bias body, 8-wave version: [6144,2048]@[2048,16] skinny MFMA, 16 tokens/wave
// ---------------------------------------------------------------------------
__device__ __forceinline__ void bias_body8(
    const u16* __restrict__ kvb, const u16* __restrict__ relb,
    const u16* __restrict__ wuvb, float* __restrict__ bias, int bblk)
{
    const int tid = threadIdx.x;
    const int wave = tid >> 6, lane = tid & 63;
    const int l16 = lane & 15, quad = lane >> 4;
    const int tBase = bblk * 128 + wave * 16;

    floatx4 acc = {0.f, 0.f, 0.f, 0.f};
    const u16* arow_kv  = kvb  + (size_t)(tBase + l16) * 1024;
    const u16* arow_rel = relb + (size_t)(tBase + l16) * 1024;
    const u16* brow     = wuvb + (size_t)l16 * 2048;

    for (int ks = 0; ks < 64; ks++) {
        const int k0 = ks * 32;
        const u16* ap = (k0 < 1024) ? (arow_kv + k0) : (arow_rel + k0 - 1024);
        short8 af = *(const short8*)(ap + quad * 8);
        short8 bf = *(const short8*)(brow + k0 + quad * 8);
        acc = __builtin_amdgcn_mfma_f32_16x16x32_bf16(af, bf, acc, 0, 0, 0);
    }
    for (int rg = 0; rg < 4; rg++) {
        const int tg = tBase + quad * 4 + rg;
        const int b = tg / 1536, t = tg % 1536;
        bias[((size_t)b * 16 + l16) * 1536 + t] = acc[rg];
    }
}

// ---------------------------------------------------------------------------
// Fused projection dispatch v2: 304 blocks x 512 threads
//   (KR 96 | V 96 | Q 64 | bias 48), heavy (K=2048) blocks first.
// ---------------------------------------------------------------------------
__global__ __launch_bounds__(512) void fused_proj_v2(
    const u16* __restrict__ qb, const u16* __restrict__ kvb,
    const u16* __restrict__ relb,
    const u16* __restrict__ WqT, const u16* __restrict__ WkrT,
    const u16* __restrict__ WvT, const u16* __restrict__ wuvb,
    u16* __restrict__ Qh, u16* __restrict__ KRh, u16* __restrict__ Vt,
    float* __restrict__ bias)
{
    __shared__ __align__(128) u16 As[4 * 256 * 32];  // 64KB: 4-slot A ring
    __shared__ __align__(128) u16 Bs[4 * 256 * 32];  // 64KB: 4-slot B ring
    const int blk = blockIdx.x;
    if (blk < 96) {
        // KR: M=6144 K=2048 (kvb for tiles 0..15, relb for 16..31), T=1536
        gemm256_body<0, 1536>(kvb, relb, WkrT, KRh, 2048, 32, 16,
                              blk % 24, blk / 24, As, Bs);
    } else if (blk < 192) {
        const int i = blk - 96;   // V: M=6144 K=1024, head-transposed out
        gemm256_body<2, 1536>(kvb, kvb, WvT, Vt, 1024, 16, 99,
                              i % 24, i / 24, As, Bs);
    } else if (blk < 256) {
        const int i = blk - 192;  // Q: M=4096 K=1024, T=1024
        gemm256_body<0, 1024>(qb, qb, WqT, Qh, 1024, 16, 99,
                              i % 16, i / 16, As, Bs);
    } else {
        bias_body8(kvb, relb, wuvb, bias, blk - 256);
    }
}

// ---------------------------------------------------------------------------
// Output GEMM, split-K=2 (grid (32,8,2) = 512 blocks = 2/CU): raw fp32
// partials to outp + z*4M; LayerNorm sums partials + residual.
// ---------------------------------------------------------------------------
__global__ __launch_bounds__(256) void out_gemm(
    const u16* __restrict__ ctx, const u16* __restrict__ WoT,
    float* __restrict__ outp)
{
    __shared__ u16 smem[2 * 128 * 32];
    const int z = blockIdx.z;
    gemm_body<3>(ctx, nullptr, WoT,
                 outp + (size_t)z * 4 * 1024 * 1024, 1024,
                 z * 512, z * 512 + 512, 1024, 1024,
                 blockIdx.x, blockIdx.y, smem, smem + 128 * 32);
}

// ---------------------------------------------------------------------------
// Flash attention (round-4 tuning, 83.8 µs): 32 q/wave for load-ILP.
// No barriers; V pre-transposed; P via per-wave LDS; exact softmax, no max.
// 512 blocks: blk&63 = (b,h) XCD-residue swizzle.
// ---------------------------------------------------------------------------
__global__ __launch_bounds__(256) void attn_kernel(
    const u16* __restrict__ Qh,   // [B][H][1024][64]
    const u16* __restrict__ KRh,  // [B][H][1536][64]
    const u16* __restrict__ Vt,   // [B][H][64][1536]
    const float* __restrict__ bias, // [B][H][1536]
    u16* __restrict__ ctx)        // [B][1024][1024] token-major
{
    const int blk  = blockIdx.x;
    const int hb   = blk & 63;
    const int qblk = blk >> 6;
    const int b = hb >> 4, h = hb & 15;
    const int tid = threadIdx.x;
    const int wave = tid >> 6, lane = tid & 63;
    const int l16 = lane & 15, quad = lane >> 4;
    const int q0 = qblk * 128;

    const u16* Qp = Qh  + (size_t)hb * 1024 * 64;
    const u16* Kp = KRh + (size_t)hb * 1536 * 64;
    const u16* Vp = Vt  + (size_t)hb * 64 * 1536;
    const float* bp = bias + (size_t)hb * 1536;

    __shared__ u16 Ps[4][2][16][68];

    short8 aq[2][2];
    for (int mi = 0; mi < 2; mi++)
        for (int ks = 0; ks < 2; ks++)
            aq[mi][ks] = *(const short8*)
                &Qp[(size_t)(q0 + wave * 32 + mi * 16 + l16) * 64 + ks * 32 + quad * 8];

    const floatx4 zf = {0.f, 0.f, 0.f, 0.f};
    floatx4 accO[2][4];
    float lsum[2][4];
    for (int mi = 0; mi < 2; mi++)
        for (int j = 0; j < 4; j++) accO[mi][j] = zf;
    for (int mi = 0; mi < 2; mi++)
        for (int rg = 0; rg < 4; rg++) lsum[mi][rg] = 0.f;

    const int nkt = 2 * qblk + 10;
    for (int kt = 0; kt < nkt; kt++) {
        const int k0 = kt * 64;

        short8 bk[4][2], bv[4][2];
        float bcol[4];
        for (int n = 0; n < 4; n++)
            for (int ks = 0; ks < 2; ks++)
                bk[n][ks] = *(const short8*)
                    &Kp[(size_t)(k0 + n * 16 + l16) * 64 + ks * 32 + quad * 8];
        for (int j = 0; j < 4; j++)
            for (int ks = 0; ks < 2; ks++)
                bv[j][ks] = *(const short8*)
                    &Vp[(size_t)(j * 16 + l16) * 1536 + k0 + ks * 32 + quad * 8];
        for (int n = 0; n < 4; n++) bcol[n] = bp[k0 + n * 16 + l16];

        const bool domask = (k0 + 63 > q0 + 512);

        for (int mi = 0; mi < 2; mi++) {
            floatx4 accS[4];
            for (int n = 0; n < 4; n++) {
                accS[n] = zf;
                for (int ks = 0; ks < 2; ks++)
                    accS[n] = __builtin_amdgcn_mfma_f32_16x16x32_bf16(
                        aq[mi][ks], bk[n][ks], accS[n], 0, 0, 0);
            }
            const int qrow = q0 + wave * 32 + mi * 16 + quad * 4;
            for (int n = 0; n < 4; n++) {
                const int col = k0 + n * 16 + l16;
                for (int rg = 0; rg < 4; rg++) {
                    float s = (accS[n][rg] + bcol[n]) * 0.125f;
                    if (domask && col > qrow + rg + 512) s = -1e30f;
                    const float p = __expf(s);
                    lsum[mi][rg] += p;
                    Ps[wave][mi][quad * 4 + rg][n * 16 + l16] = f2bf(p);
                }
            }
            short8 ap[2];
            for (int ks = 0; ks < 2; ks++)
                ap[ks] = *(const short8*)&Ps[wave][mi][l16][ks * 32 + quad * 8];
            for (int j = 0; j < 4; j++)
                for (int ks = 0; ks < 2; ks++)
                    accO[mi][j] = __builtin_amdgcn_mfma_f32_16x16x32_bf16(
                        ap[ks], bv[j][ks], accO[mi][j], 0, 0, 0);
        }
    }

    for (int mi = 0; mi < 2; mi++)
        for (int rg = 0; rg < 4; rg++) {
            float s = lsum[mi][rg];
            for (int off = 1; off < 16; off <<= 1) s += __shfl_xor(s, off, 64);
            lsum[mi][rg] = s;
        }

    for (int mi = 0; mi < 2; mi++)
        for (int j = 0; j < 4; j++)
            for (int rg = 0; rg < 4; rg++) {
                const int q = q0 + wave * 32 + mi * 16 + quad * 4 + rg;
                const int d = j * 16 + l16;
                ctx[((size_t)b * 1024 + q) * 1024 + h * 64 + d] =
                    f2bf(accO[mi][j][rg] / lsum[mi][rg]);
            }
}

// ---------------------------------------------------------------------------
// LayerNorm over (partial0 + partial1 + residual query): fp32 -> fp32 d_out
// ---------------------------------------------------------------------------
__global__ __launch_bounds__(256) void ln_kernel(
    const float* __restrict__ x0, const float* __restrict__ x1,
    const float* __restrict__ q,
    const float* __restrict__ gamma, const float* __restrict__ beta,
    float* __restrict__ out)
{
    const int row = blockIdx.x;
    const int tid = threadIdx.x;
    const size_t base = (size_t)row * 1024 + tid * 4;
    float4 a = *(const float4*)&x0[base];
    float4 c = *(const float4*)&x1[base];
    float4 r = *(const float4*)&q[base];
    float4 v;
    v.x = a.x + c.x + r.x; v.y = a.y + c.y + r.y;
    v.z = a.z + c.z + r.z; v.w = a.w + c.w + r.w;
    float s  = v.x + v.y + v.z + v.w;
    float ss = v.x * v.x + v.y * v.y + v.z * v.z + v.w * v.w;
    for (int off = 1; off < 64; off <<= 1) {
        s  += __shfl_xor(s, off, 64);
        ss += __shfl_xor(ss, off, 64);
    }
    __shared__ float sm[8];
    const int wave = tid >> 6, lane = tid & 63;
    if (lane == 0) { sm[wave] = s; sm[4 + wave] = ss; }
    __syncthreads();
    s  = sm[0] + sm[1] + sm[2] + sm[3];
    ss = sm[4] + sm[5] + sm[6] + sm[7];
    const float mu  = s * (1.f / 1024.f);
    const float var = ss * (1.f / 1024.f) - mu * mu;
    const float inv = rsqrtf(var + 1e-5f);
    float* op = out + (size_t)row * 1024;
    const float* ve = &v.x;
    for (int j = 0; j < 4; j++) {
        const int c2 = tid * 4 + j;
        op[c2] = (ve[j] - mu) * inv * gamma[c2] + beta[c2];
    }
}

// ---------------------------------------------------------------------------
extern "C" void kernel_launch(void* const* d_in, const int* in_sizes, int n_in,
                              void* d_out, int out_size, void* d_ws, size_t ws_size,
                              hipStream_t stream)
{
    const float* query     = (const float*)d_in[0];
    const float* key_value = (const float*)d_in[1];
    const float* relative  = (const float*)d_in[2];
    // d_in[3] = mask: analytic (j <= i+512), unused
    const float* Wq = (const float*)d_in[4];
    const float* Wk = (const float*)d_in[5];
    const float* Wv = (const float*)d_in[6];
    const float* Wr = (const float*)d_in[7];
    const float* Wo = (const float*)d_in[8];
    const float* u  = (const float*)d_in[9];
    const float* v  = (const float*)d_in[10];
    const float* gamma = (const float*)d_in[11];
    const float* beta  = (const float*)d_in[12];

    char* wsp = (char*)d_ws;
    auto alloc = [&](size_t bytes) -> char* {
        char* p = wsp; wsp += (bytes + 255) & ~(size_t)255; return p;
    };
    u16*   qb   = (u16*)alloc((size_t)4 * 1024 * 1024 * 2);
    u16*   kvb  = (u16*)alloc((size_t)4 * 1536 * 1024 * 2);
    u16*   relb = (u16*)alloc((size_t)4 * 1536 * 1024 * 2);
    u16*   WqT  = (u16*)alloc((size_t)1024 * 1024 * 2);
    u16*   WkrT = (u16*)alloc((size_t)1024 * 2048 * 2);
    u16*   WvT  = (u16*)alloc((size_t)1024 * 1024 * 2);
    u16*   WoT  = (u16*)alloc((size_t)1024 * 1024 * 2);
    u16*   wuvb = (u16*)alloc((size_t)16 * 2048 * 2);
    u16*   Qh   = (u16*)alloc((size_t)4 * 16 * 1024 * 64 * 2);
    u16*   KRh  = (u16*)alloc((size_t)4 * 16 * 1536 * 64 * 2);
    u16*   Vt   = (u16*)alloc((size_t)4 * 16 * 64 * 1536 * 2);
    float* bias = (float*)alloc((size_t)4 * 16 * 1536 * 4);
    u16*   ctx  = (u16*)alloc((size_t)4 * 1024 * 1024 * 2);
    float* outp = (float*)alloc((size_t)2 * 4 * 1024 * 1024 * 4);  // 2 split-K partials

    const dim3 tb(256);
    cvt3_kernel<<<dim3(3072, 3), tb, 0, stream>>>(
        query, qb, 4 * 1024 * 1024,
        key_value, kvb, 4 * 1536 * 1024,
        relative, relb, 4 * 1536 * 1024);

    transpose5_kernel<<<dim3(16, 16, 5), tb, 0, stream>>>(
        Wq, Wk, Wr, Wv, Wo, WqT, WkrT, WvT, WoT);
    wuv_kernel<<<64, tb, 0, stream>>>(Wk, Wr, u, v, wuvb);

    fused_proj_v2<<<dim3(304), dim3(512), 0, stream>>>(
        qb, kvb, relb, WqT, WkrT, WvT, wuvb, Qh, KRh, Vt, bias);

    attn_kernel<<<dim3(512), tb, 0, stream>>>(Qh, KRh, Vt, bias, ctx);

    out_gemm<<<dim3(32, 8, 2), tb, 0, stream>>>(ctx, WoT, outp);
    ln_kernel<<<4096, tb, 0, stream>>>(
        outp, outp + (size_t)4 * 1024 * 1024, query, gamma, beta, (float*)d_out);
}